// Round 11
// baseline (664.018 us; speedup 1.0000x reference)
//
#include <hip/hip_runtime.h>

#define N_NODES 100000
#define M_PAD   100096   // multiple of 128 rows
#define N_EDGES 3200000
#define DIM 128
#define N_LAYERS 3
#define NUM_GRAPHS 128
#define BN_EPS 1e-5f

// ---- binned CSR build parameters ----
#define DST_SHIFT 7
#define BUCKET_NODES 128
#define N_BUCKETS ((N_NODES + BUCKET_NODES - 1) / BUCKET_NODES)  // 782
#define BUCKET_CAP 4864
#define EDGES_PER_BLOCK 16384
#define BIN_BLOCKS ((N_EDGES + EDGES_PER_BLOCK - 1) / EDGES_PER_BLOCK)  // 196
#define N_BANDS 64   // used: (src>>11) in [0,49)

#define AGG_BLOCKS 25000          // 4 nodes per block; 25000 % 8 == 0
#define AGG_CHUNK  (AGG_BLOCKS / 8)   // 3125 blocks per XCD

typedef unsigned int uint32;
typedef unsigned short u16;
typedef __attribute__((ext_vector_type(8))) short bf16x8;
typedef __attribute__((ext_vector_type(4))) float f32x4;

__device__ __forceinline__ float bf2f(u16 u) {
    union { uint32 i; float f; } c;
    c.i = ((uint32)u) << 16;
    return c.f;
}
__device__ __forceinline__ u16 f2bf(float f) {
    union { float f; uint32 i; } c;
    c.f = f;
    uint32 i = c.i;
    return (u16)((i + 0x7FFFu + ((i >> 16) & 1u)) >> 16);
}
__device__ __forceinline__ float lo_bf(uint32 v) {
    union { uint32 i; float f; } c;
    c.i = v << 16;
    return c.f;
}
__device__ __forceinline__ float hi_bf(uint32 v) {
    union { uint32 i; float f; } c;
    c.i = v & 0xFFFF0000u;
    return c.f;
}
__device__ __forceinline__ uint32 pack_bf2(float a, float b) {
    return ((uint32)f2bf(b) << 16) | (uint32)f2bf(a);
}
__device__ __forceinline__ void unpack_add8(float* acc, uint4 v) {
    acc[0] += lo_bf(v.x); acc[1] += hi_bf(v.x);
    acc[2] += lo_bf(v.y); acc[3] += hi_bf(v.y);
    acc[4] += lo_bf(v.z); acc[5] += hi_bf(v.z);
    acc[6] += lo_bf(v.w); acc[7] += hi_bf(v.w);
}

// ---------------------------------------------------------------------------
// zero_misc: one launch replaces all memsets
// ---------------------------------------------------------------------------
__global__ __launch_bounds__(256) void zero_misc(int* __restrict__ gcur,
                                                 float* __restrict__ bn_stats,
                                                 float* __restrict__ outp,
                                                 uint32* __restrict__ aggpad32) {
    int i = blockIdx.x * 256 + threadIdx.x;
    if (i < N_BUCKETS) gcur[i] = 0;
    if (i < N_LAYERS * 2 * DIM) bn_stats[i] = 0.f;
    if (i < NUM_GRAPHS * DIM) outp[i] = 0.f;
    if (i < (M_PAD - N_NODES) * DIM / 2) aggpad32[i] = 0;
}

// ---------------------------------------------------------------------------
// Stage A: bin edges by dst bucket (2-pass, coalesced). packed = src|(dst&127)<<17
// ---------------------------------------------------------------------------
__global__ __launch_bounds__(256) void bin_by_dst(const int* __restrict__ src,
                                                  const int* __restrict__ dst,
                                                  int* __restrict__ gcur,
                                                  uint32* __restrict__ packed) {
    __shared__ int cnt[N_BUCKETS];
    __shared__ int cur[N_BUCKETS];
    int t = threadIdx.x;
    int e0 = blockIdx.x * EDGES_PER_BLOCK;
    for (int i = t; i < N_BUCKETS; i += 256) cnt[i] = 0;
    __syncthreads();

    for (int j = 0; j < EDGES_PER_BLOCK / 256; ++j) {
        int e = e0 + j * 256 + t;
        if (e < N_EDGES) atomicAdd(&cnt[dst[e] >> DST_SHIFT], 1);
    }
    __syncthreads();
    for (int i = t; i < N_BUCKETS; i += 256) {
        int c = cnt[i];
        cur[i] = c ? atomicAdd(&gcur[i], c) : 0;
    }
    __syncthreads();
    for (int j = 0; j < EDGES_PER_BLOCK / 256; ++j) {
        int e = e0 + j * 256 + t;
        if (e < N_EDGES) {
            int d = dst[e];
            int b = d >> DST_SHIFT;
            int pos = atomicAdd(&cur[b], 1);
            if (pos < BUCKET_CAP)
                packed[(size_t)b * BUCKET_CAP + pos] =
                    (uint32)src[e] | ((uint32)(d & (BUCKET_NODES - 1)) << 17);
        }
    }
}

// ---------------------------------------------------------------------------
// exclusive scan over bucket totals (parallel: 4 elems/thread + wave scan)
// ---------------------------------------------------------------------------
__global__ __launch_bounds__(256) void scan_buckets(const int* __restrict__ gcur,
                                                    int* __restrict__ obase,
                                                    int* __restrict__ row_ptr) {
    int t = threadIdx.x;
    int lane = t & 63, wid = t >> 6;
    int v[4];
    int sum = 0;
#pragma unroll
    for (int j = 0; j < 4; ++j) {
        int idx = t * 4 + j;
        int c = 0;
        if (idx < N_BUCKETS) {
            c = gcur[idx];
            if (c > BUCKET_CAP) c = BUCKET_CAP;
        }
        v[j] = c;
        sum += c;
    }
    int x = sum;
#pragma unroll
    for (int off = 1; off < 64; off <<= 1) {
        int y = __shfl_up(x, off);
        if (lane >= off) x += y;
    }
    __shared__ int wsum[4];
    if (lane == 63) wsum[wid] = x;
    __syncthreads();
    int wexcl = 0;
    for (int w = 0; w < wid; ++w) wexcl += wsum[w];
    int run = wexcl + (x - sum);
#pragma unroll
    for (int j = 0; j < 4; ++j) {
        int idx = t * 4 + j;
        if (idx < N_BUCKETS) obase[idx] = run;
        run += v[j];
    }
    if (t == 255) row_ptr[N_NODES] = run;
}

// ---------------------------------------------------------------------------
// Stage B: per bucket — row_ptr, band-sort by src>>11, place into col_src
// ---------------------------------------------------------------------------
__global__ __launch_bounds__(256) void build_buckets(const uint32* __restrict__ packed,
                                                     const int* __restrict__ gcur,
                                                     const int* __restrict__ obase_arr,
                                                     int* __restrict__ row_ptr,
                                                     int* __restrict__ col_src) {
    __shared__ uint32 ed[BUCKET_CAP];
    __shared__ uint32 ed2[BUCKET_CAP];
    __shared__ int bandcur[N_BANDS];
    __shared__ int ncnt[BUCKET_NODES];
    __shared__ int ncur[BUCKET_NODES];
    int b = blockIdx.x, t = threadIdx.x;
    int cnt = gcur[b];
    if (cnt > BUCKET_CAP) cnt = BUCKET_CAP;
    int obase = obase_arr[b];
    int n0 = b * BUCKET_NODES;

    if (t < N_BANDS) bandcur[t] = 0;
    if (t < BUCKET_NODES) ncnt[t] = 0;
    __syncthreads();

    const uint32* reg = packed + (size_t)b * BUCKET_CAP;
    for (int i = t; i < cnt; i += 256) {
        uint32 v = reg[i];
        ed[i] = v;
        atomicAdd(&bandcur[(v & 0x1FFFFu) >> 11], 1);
        atomicAdd(&ncnt[v >> 17], 1);
    }
    __syncthreads();

    if (t == 0) {
        int run = 0;
        for (int w = 0; w < N_BANDS; ++w) {
            int c = bandcur[w];
            bandcur[w] = run;
            run += c;
        }
    }
    int myc = (t < BUCKET_NODES) ? ncnt[t] : 0;
    if (t < BUCKET_NODES) ncur[t] = myc;
    __syncthreads();
    for (int off = 1; off < BUCKET_NODES; off <<= 1) {
        int v = 0;
        if (t < BUCKET_NODES && t >= off) v = ncur[t - off];
        __syncthreads();
        if (t < BUCKET_NODES) ncur[t] += v;
        __syncthreads();
    }
    if (t < BUCKET_NODES) {
        int excl = ncur[t] - myc;
        ncur[t] = excl;
        int gn = n0 + t;
        if (gn < N_NODES) row_ptr[gn] = obase + excl;
    }
    __syncthreads();

    // counting sort by src band
    for (int i = t; i < cnt; i += 256) {
        uint32 v = ed[i];
        int p = atomicAdd(&bandcur[(v & 0x1FFFFu) >> 11], 1);
        ed2[p] = v;
    }
    __syncthreads();

    for (int i = t; i < cnt; i += 256) {
        uint32 v = ed2[i];
        int slot = atomicAdd(&ncur[v >> 17], 1);
        col_src[obase + slot] = (int)(v & 0x1FFFFu);
    }
}

// ---------------------------------------------------------------------------
// All 7 weight matrices -> WT bf16, transposed (n-major) AND pre-swizzled:
// element (n,k) at byte (n*256 + k*2) ^ ((n&7)<<4) within its matrix.
// ---------------------------------------------------------------------------
__global__ void cvt_wt_all(const float* __restrict__ Wn, const float* __restrict__ W1,
                           const float* __restrict__ W2, u16* __restrict__ WT) {
    int m = blockIdx.x >> 7, n = blockIdx.x & 127, k = threadIdx.x;
    const float* src = (m == 0) ? Wn
                     : (m <= 3) ? W1 + (size_t)(m - 1) * DIM * DIM
                                : W2 + (size_t)(m - 4) * DIM * DIM;
    int L = n * 256 + k * 2;
    int Ls = L ^ ((n & 7) << 4);
    *(u16*)((char*)WT + (size_t)m * 32768 + Ls) = f2bf(src[(size_t)k * DIM + n]);
}

// ---------------------------------------------------------------------------
// Aggregation (row-major, quad-per-edge): one wave per node; quad q loads one
// full 256 B row per edge via dwordx4 (16 B/lane), 4 edges in flight; f32
// accum; cross-quad shfl reduce. (XCD swizzle kept: neutral, r10.)
// ---------------------------------------------------------------------------
__global__ __launch_bounds__(256) void aggregate_bf(const u16* __restrict__ h,
                                                    const int* __restrict__ row_ptr,
                                                    const int* __restrict__ col_src,
                                                    u16* __restrict__ agg) {
    int wg = (blockIdx.x & 7) * AGG_CHUNK + (blockIdx.x >> 3);  // bijective
    int wv = wg * 4 + (threadIdx.x >> 6);
    int lane = threadIdx.x & 63;
    int q = lane >> 4, c = lane & 15;
    if (wv >= N_NODES) return;
    int beg = row_ptr[wv], end = row_ptr[wv + 1];
    const uint4* h4 = (const uint4*)h;   // one row = 16 uint4

    float acc[8];
#pragma unroll
    for (int j = 0; j < 8; ++j) acc[j] = 0.f;

    if (q == 0) {  // self contribution (1+eps)*h, eps=0
        uint4 v = h4[(size_t)wv * 16 + c];
        unpack_add8(acc, v);
    }
    int e = beg + q;
    for (; e + 12 < end; e += 16) {
        int i0 = col_src[e];
        int i1 = col_src[e + 4];
        int i2 = col_src[e + 8];
        int i3 = col_src[e + 12];
        uint4 v0 = h4[(size_t)i0 * 16 + c];
        uint4 v1 = h4[(size_t)i1 * 16 + c];
        uint4 v2 = h4[(size_t)i2 * 16 + c];
        uint4 v3 = h4[(size_t)i3 * 16 + c];
        unpack_add8(acc, v0);
        unpack_add8(acc, v1);
        unpack_add8(acc, v2);
        unpack_add8(acc, v3);
    }
    for (; e < end; e += 4) {
        uint4 v0 = h4[(size_t)col_src[e] * 16 + c];
        unpack_add8(acc, v0);
    }
#pragma unroll
    for (int j = 0; j < 8; ++j) {
        acc[j] += __shfl_xor(acc[j], 16);
        acc[j] += __shfl_xor(acc[j], 32);
    }
    if (q == 0) {
        uint4 o;
        o.x = pack_bf2(acc[0], acc[1]);
        o.y = pack_bf2(acc[2], acc[3]);
        o.z = pack_bf2(acc[4], acc[5]);
        o.w = pack_bf2(acc[6], acc[7]);
        *(uint4*)&agg[(size_t)wv * DIM + c * 8] = o;
    }
}

// ---------------------------------------------------------------------------
// GEMM v3: 128 rows x 128 cols per block (256 thr = 4 waves).
// B (32 KB, pre-swizzled) in LDS; A loads hoisted before the stage barrier.
// MODE 0: A = f32 x (fused cvt)              -> h = A@W + b
// MODE 1: A = bf16 agg, BN stats epilogue    -> y = A@W1 + b1
// MODE 2: A = bf16 y, BN+ReLU pre, ReLU post -> h = relu(relu(BN(y))@W2+b2)
// MODE 3: MODE 2 + fused global-add-pool epilogue, NO h write (last layer)
// ---------------------------------------------------------------------------
template <int MODE>
__global__ __launch_bounds__(256) void gemm_v3(const void* __restrict__ Av,
                                               const u16* __restrict__ WTs,
                                               const float* __restrict__ bias,
                                               u16* __restrict__ outp,
                                               float* __restrict__ bn_sum,
                                               float* __restrict__ bn_sumsq,
                                               const float* __restrict__ gamma,
                                               const float* __restrict__ beta,
                                               const int* __restrict__ batchp,
                                               float* __restrict__ poolout) {
    __shared__ u16 sB[DIM * DIM];     // 32 KB swizzled
    __shared__ float sc_[DIM];
    __shared__ float sh_[DIM];
    __shared__ float lsq[8][DIM];     // MODE1: stats; MODE3: pool tile

    int t = threadIdx.x;
    int wid = t >> 6, lane = t & 63;
    int hw = lane >> 4, c = lane & 15;
    int row0 = blockIdx.x * 128 + wid * 32;

    // ---- issue A loads FIRST ----
    bf16x8 a[2][4];
    float4 af[2][4][2];
#pragma unroll
    for (int rf = 0; rf < 2; ++rf) {
        int row = row0 + rf * 16 + c;
#pragma unroll
        for (int ks = 0; ks < 4; ++ks) {
            int k0 = ks * 32 + hw * 8;
            if (MODE == 0) {
                const float* xf = (const float*)Av;
                af[rf][ks][0] = make_float4(0.f, 0.f, 0.f, 0.f);
                af[rf][ks][1] = af[rf][ks][0];
                if (row < N_NODES) {
                    af[rf][ks][0] = *(const float4*)&xf[(size_t)row * DIM + k0];
                    af[rf][ks][1] = *(const float4*)&xf[(size_t)row * DIM + k0 + 4];
                }
            } else {
                const u16* Ab = (const u16*)Av;
                a[rf][ks] = *(const bf16x8*)&Ab[(size_t)row * DIM + k0];
            }
        }
    }

    // ---- stage B (linear copy; swizzle baked into global layout) ----
    {
        const uint4* Wg = (const uint4*)WTs;
        uint4* sB4 = (uint4*)sB;
#pragma unroll
        for (int i = 0; i < 8; ++i) sB4[i * 256 + t] = Wg[i * 256 + t];
    }
    if ((MODE == 2 || MODE == 3) && t < DIM) {
        const float invN = 1.0f / (float)N_NODES;
        float mean = bn_sum[t] * invN;
        float var = fmaxf(bn_sumsq[t] * invN - mean * mean, 0.f);
        float rs = rsqrtf(var + BN_EPS);
        float sc = gamma[t] * rs;
        sc_[t] = sc;
        sh_[t] = beta[t] - mean * sc;
    }
    if (MODE == 3) {
        for (int i = t; i < 8 * DIM; i += 256) ((float*)lsq)[i] = 0.f;
    }
    __syncthreads();

    // ---- finish A fragments in registers ----
#pragma unroll
    for (int rf = 0; rf < 2; ++rf) {
#pragma unroll
        for (int ks = 0; ks < 4; ++ks) {
            int k0 = ks * 32 + hw * 8;
            if (MODE == 0) {
                union { bf16x8 v; u16 u[8]; } ua;
                float4 v0 = af[rf][ks][0], v1 = af[rf][ks][1];
                ua.u[0] = f2bf(v0.x); ua.u[1] = f2bf(v0.y);
                ua.u[2] = f2bf(v0.z); ua.u[3] = f2bf(v0.w);
                ua.u[4] = f2bf(v1.x); ua.u[5] = f2bf(v1.y);
                ua.u[6] = f2bf(v1.z); ua.u[7] = f2bf(v1.w);
                a[rf][ks] = ua.v;
            } else if (MODE == 2 || MODE == 3) {
                union { bf16x8 v; u16 u[8]; } ua;
                ua.v = a[rf][ks];
#pragma unroll
                for (int j = 0; j < 8; ++j) {
                    float f = bf2f(ua.u[j]);
                    f = fmaxf(fmaf(f, sc_[k0 + j], sh_[k0 + j]), 0.f);
                    ua.u[j] = f2bf(f);
                }
                a[rf][ks] = ua.v;
            }
        }
    }

    // ---- MFMA from LDS B ----
    f32x4 acc[2][8];
#pragma unroll
    for (int rf = 0; rf < 2; ++rf)
#pragma unroll
        for (int nf = 0; nf < 8; ++nf) acc[rf][nf] = (f32x4){0.f, 0.f, 0.f, 0.f};

    int swz = (c & 7) << 4;
#pragma unroll
    for (int ks = 0; ks < 4; ++ks) {
#pragma unroll
        for (int nf = 0; nf < 8; ++nf) {
            int L = (nf * 4096 + c * 256 + ks * 64 + hw * 16) ^ swz;
            bf16x8 b = *(const bf16x8*)((const char*)sB + L);
            acc[0][nf] = __builtin_amdgcn_mfma_f32_16x16x32_bf16(a[0][ks], b, acc[0][nf], 0, 0, 0);
            acc[1][nf] = __builtin_amdgcn_mfma_f32_16x16x32_bf16(a[1][ks], b, acc[1][nf], 0, 0, 0);
        }
    }

    // ---- epilogue ----
    float s_[8], q_[8];
#pragma unroll
    for (int nf = 0; nf < 8; ++nf) { s_[nf] = 0.f; q_[nf] = 0.f; }

    // MODE 3: graph ids for this thread's 8 rows (relative to block's gmin)
    int gmin = 0;
    int gg[2][4];
    if (MODE == 3) {
        gmin = batchp[blockIdx.x * 128];   // row0_blk < N_NODES always
#pragma unroll
        for (int rf = 0; rf < 2; ++rf) {
            int rbase = row0 + rf * 16 + hw * 4;
#pragma unroll
            for (int r = 0; r < 4; ++r) {
                int row = rbase + r;
                gg[rf][r] = (row < N_NODES) ? (batchp[row] - gmin) : -1;
            }
        }
    }

#pragma unroll
    for (int rf = 0; rf < 2; ++rf) {
        int rbase = row0 + rf * 16 + hw * 4;
#pragma unroll
        for (int nf = 0; nf < 8; ++nf) {
            float bv = bias[nf * 16 + c];
#pragma unroll
            for (int r = 0; r < 4; ++r) {
                float v = acc[rf][nf][r] + bv;
                if (MODE == 2 || MODE == 3) v = fmaxf(v, 0.f);
                if (MODE == 3) {
                    int s = gg[rf][r];
                    if (s >= 0) {
                        if (s < 8)
                            atomicAdd(&lsq[s][nf * 16 + c], v);
                        else
                            atomicAdd(&poolout[(gmin + s) * DIM + nf * 16 + c], v);
                    }
                } else {
                    outp[(size_t)(rbase + r) * DIM + nf * 16 + c] = f2bf(v);
                    if (MODE == 1) {
                        float m = (rbase + r < N_NODES) ? v : 0.f;
                        s_[nf] += m;
                        q_[nf] += m * m;
                    }
                }
            }
        }
    }

    if (MODE == 1) {
#pragma unroll
        for (int nf = 0; nf < 8; ++nf) {
            s_[nf] += __shfl_xor(s_[nf], 16);
            s_[nf] += __shfl_xor(s_[nf], 32);
            q_[nf] += __shfl_xor(q_[nf], 16);
            q_[nf] += __shfl_xor(q_[nf], 32);
        }
        if (lane < 16) {
#pragma unroll
            for (int nf = 0; nf < 8; ++nf) {
                lsq[wid][nf * 16 + c] = s_[nf];
                lsq[4 + wid][nf * 16 + c] = q_[nf];
            }
        }
        __syncthreads();
        if (t < DIM) {
            atomicAdd(&bn_sum[t], lsq[0][t] + lsq[1][t] + lsq[2][t] + lsq[3][t]);
            atomicAdd(&bn_sumsq[t], lsq[4][t] + lsq[5][t] + lsq[6][t] + lsq[7][t]);
        }
    }

    if (MODE == 3) {
        __syncthreads();
        for (int i = t; i < 8 * DIM; i += 256) {
            float v = ((float*)lsq)[i];
            if (v != 0.f) {
                int slot = i >> 7, col = i & 127;
                atomicAdd(&poolout[(gmin + slot) * DIM + col], v);
            }
        }
    }
}

// ---------------------------------------------------------------------------
extern "C" void kernel_launch(void* const* d_in, const int* in_sizes, int n_in,
                              void* d_out, int out_size, void* d_ws, size_t ws_size,
                              hipStream_t stream) {
    const float* x     = (const float*)d_in[0];
    const int*   ei    = (const int*)d_in[1];
    const int*   batch = (const int*)d_in[2];
    const float* Wn    = (const float*)d_in[3];
    const float* bnode = (const float*)d_in[4];
    const float* W1    = (const float*)d_in[5];
    const float* b1    = (const float*)d_in[6];
    const float* gamma = (const float*)d_in[7];
    const float* beta  = (const float*)d_in[8];
    const float* W2    = (const float*)d_in[9];
    const float* b2    = (const float*)d_in[10];
    float* out = (float*)d_out;

    const int* e_src = ei;
    const int* e_dst = ei + N_EDGES;

    // workspace layout
    const size_t MD = (size_t)M_PAD * DIM;
    u16* h   = (u16*)d_ws;                  // row-major
    u16* agg = h + MD;                      // row-major
    u16* y   = agg + MD;                    // row-major
    u16* WT  = y + MD;                      // 7 * 128 * 128 bf16, pre-swizzled
    int* row_ptr = (int*)(WT + 7 * DIM * DIM);
    int* col_src = row_ptr + N_NODES + 1;
    int* gcur    = col_src + N_EDGES;
    int* obase   = gcur + N_BUCKETS;
    float* bn_stats = (float*)(obase + N_BUCKETS);   // 3 layers * 2 * DIM
    // packed aliases y: used only during CSR build, before any GEMM writes y
    uint32* packed = (uint32*)y;            // 782*4864*4 B = 15.2 MB <= 25.6 MB

    const int GEMM_BLOCKS = M_PAD / 128;    // 782

    // ---- init + CSR build ----
    zero_misc<<<64, 256, 0, stream>>>(gcur, bn_stats, out,
                                      (uint32*)(agg + (size_t)N_NODES * DIM));
    bin_by_dst<<<BIN_BLOCKS, 256, 0, stream>>>(e_src, e_dst, gcur, packed);
    scan_buckets<<<1, 256, 0, stream>>>(gcur, obase, row_ptr);
    build_buckets<<<N_BUCKETS, 256, 0, stream>>>(packed, gcur, obase, row_ptr, col_src);

    // ---- weights (transposed + swizzled bf16) ----
    cvt_wt_all<<<7 * DIM, DIM, 0, stream>>>(Wn, W1, W2, WT);

    // ---- node encoder (fused f32->bf16) ----
    gemm_v3<0><<<GEMM_BLOCKS, 256, 0, stream>>>(x, WT, bnode, h, nullptr,
                                                nullptr, nullptr, nullptr,
                                                nullptr, nullptr);

    // ---- GIN layers ----
    for (int i = 0; i < N_LAYERS; ++i) {
        float* bn_sum = bn_stats + (size_t)i * 2 * DIM;
        float* bn_sumsq = bn_sum + DIM;
        aggregate_bf<<<AGG_BLOCKS, 256, 0, stream>>>(h, row_ptr, col_src, agg);
        gemm_v3<1><<<GEMM_BLOCKS, 256, 0, stream>>>(
            agg, WT + (size_t)(1 + i) * DIM * DIM, b1 + i * DIM, y, bn_sum,
            bn_sumsq, nullptr, nullptr, nullptr, nullptr);
        if (i < N_LAYERS - 1) {
            gemm_v3<2><<<GEMM_BLOCKS, 256, 0, stream>>>(
                y, WT + (size_t)(4 + i) * DIM * DIM, b2 + i * DIM, h, bn_sum,
                bn_sumsq, gamma + i * DIM, beta + i * DIM, nullptr, nullptr);
        } else {
            // last layer: fused GEMM2 + global-add-pool, no h write
            gemm_v3<3><<<GEMM_BLOCKS, 256, 0, stream>>>(
                y, WT + (size_t)(4 + i) * DIM * DIM, b2 + i * DIM, nullptr,
                bn_sum, bn_sumsq, gamma + i * DIM, beta + i * DIM, batch, out);
        }
    }
}

// Round 12
// 605.381 us; speedup vs baseline: 1.0969x; 1.0969x over previous
//
#include <hip/hip_runtime.h>

#define N_NODES 100000
#define M_PAD   100096   // multiple of 128 rows
#define N_EDGES 3200000
#define DIM 128
#define N_LAYERS 3
#define NUM_GRAPHS 128
#define BN_EPS 1e-5f

// ---- binned CSR build parameters ----
#define DST_SHIFT 7
#define BUCKET_NODES 128
#define N_BUCKETS ((N_NODES + BUCKET_NODES - 1) / BUCKET_NODES)  // 782
#define BUCKET_CAP 4864
#define EDGES_PER_BLOCK 16384
#define BIN_BLOCKS ((N_EDGES + EDGES_PER_BLOCK - 1) / EDGES_PER_BLOCK)  // 196
#define N_BANDS 64   // used: (src>>11) in [0,49)

#define AGG_BLOCKS 25000          // 4 nodes per block; 25000 % 8 == 0
#define AGG_CHUNK  (AGG_BLOCKS / 8)   // 3125 blocks per XCD

typedef unsigned int uint32;
typedef unsigned short u16;
typedef __attribute__((ext_vector_type(8))) short bf16x8;
typedef __attribute__((ext_vector_type(4))) float f32x4;

__device__ __forceinline__ float bf2f(u16 u) {
    union { uint32 i; float f; } c;
    c.i = ((uint32)u) << 16;
    return c.f;
}
__device__ __forceinline__ u16 f2bf(float f) {
    union { float f; uint32 i; } c;
    c.f = f;
    uint32 i = c.i;
    return (u16)((i + 0x7FFFu + ((i >> 16) & 1u)) >> 16);
}
__device__ __forceinline__ float lo_bf(uint32 v) {
    union { uint32 i; float f; } c;
    c.i = v << 16;
    return c.f;
}
__device__ __forceinline__ float hi_bf(uint32 v) {
    union { uint32 i; float f; } c;
    c.i = v & 0xFFFF0000u;
    return c.f;
}
__device__ __forceinline__ uint32 pack_bf2(float a, float b) {
    return ((uint32)f2bf(b) << 16) | (uint32)f2bf(a);
}
__device__ __forceinline__ void unpack_add8(float* acc, uint4 v) {
    acc[0] += lo_bf(v.x); acc[1] += hi_bf(v.x);
    acc[2] += lo_bf(v.y); acc[3] += hi_bf(v.y);
    acc[4] += lo_bf(v.z); acc[5] += hi_bf(v.z);
    acc[6] += lo_bf(v.w); acc[7] += hi_bf(v.w);
}

// ---------------------------------------------------------------------------
// zero_misc: one launch replaces all memsets
// ---------------------------------------------------------------------------
__global__ __launch_bounds__(256) void zero_misc(int* __restrict__ gcur,
                                                 float* __restrict__ bn_stats,
                                                 float* __restrict__ outp,
                                                 uint32* __restrict__ aggpad32) {
    int i = blockIdx.x * 256 + threadIdx.x;
    if (i < N_BUCKETS) gcur[i] = 0;
    if (i < N_LAYERS * 2 * DIM) bn_stats[i] = 0.f;
    if (i < NUM_GRAPHS * DIM) outp[i] = 0.f;
    if (i < (M_PAD - N_NODES) * DIM / 2) aggpad32[i] = 0;
}

// ---------------------------------------------------------------------------
// Stage A: bin edges by dst bucket (2-pass, coalesced). packed = src|(dst&127)<<17
// ---------------------------------------------------------------------------
__global__ __launch_bounds__(256) void bin_by_dst(const int* __restrict__ src,
                                                  const int* __restrict__ dst,
                                                  int* __restrict__ gcur,
                                                  uint32* __restrict__ packed) {
    __shared__ int cnt[N_BUCKETS];
    __shared__ int cur[N_BUCKETS];
    int t = threadIdx.x;
    int e0 = blockIdx.x * EDGES_PER_BLOCK;
    for (int i = t; i < N_BUCKETS; i += 256) cnt[i] = 0;
    __syncthreads();

    for (int j = 0; j < EDGES_PER_BLOCK / 256; ++j) {
        int e = e0 + j * 256 + t;
        if (e < N_EDGES) atomicAdd(&cnt[dst[e] >> DST_SHIFT], 1);
    }
    __syncthreads();
    for (int i = t; i < N_BUCKETS; i += 256) {
        int c = cnt[i];
        cur[i] = c ? atomicAdd(&gcur[i], c) : 0;
    }
    __syncthreads();
    for (int j = 0; j < EDGES_PER_BLOCK / 256; ++j) {
        int e = e0 + j * 256 + t;
        if (e < N_EDGES) {
            int d = dst[e];
            int b = d >> DST_SHIFT;
            int pos = atomicAdd(&cur[b], 1);
            if (pos < BUCKET_CAP)
                packed[(size_t)b * BUCKET_CAP + pos] =
                    (uint32)src[e] | ((uint32)(d & (BUCKET_NODES - 1)) << 17);
        }
    }
}

// ---------------------------------------------------------------------------
// exclusive scan over bucket totals (parallel: 4 elems/thread + wave scan)
// ---------------------------------------------------------------------------
__global__ __launch_bounds__(256) void scan_buckets(const int* __restrict__ gcur,
                                                    int* __restrict__ obase,
                                                    int* __restrict__ row_ptr) {
    int t = threadIdx.x;
    int lane = t & 63, wid = t >> 6;
    int v[4];
    int sum = 0;
#pragma unroll
    for (int j = 0; j < 4; ++j) {
        int idx = t * 4 + j;
        int c = 0;
        if (idx < N_BUCKETS) {
            c = gcur[idx];
            if (c > BUCKET_CAP) c = BUCKET_CAP;
        }
        v[j] = c;
        sum += c;
    }
    int x = sum;
#pragma unroll
    for (int off = 1; off < 64; off <<= 1) {
        int y = __shfl_up(x, off);
        if (lane >= off) x += y;
    }
    __shared__ int wsum[4];
    if (lane == 63) wsum[wid] = x;
    __syncthreads();
    int wexcl = 0;
    for (int w = 0; w < wid; ++w) wexcl += wsum[w];
    int run = wexcl + (x - sum);
#pragma unroll
    for (int j = 0; j < 4; ++j) {
        int idx = t * 4 + j;
        if (idx < N_BUCKETS) obase[idx] = run;
        run += v[j];
    }
    if (t == 255) row_ptr[N_NODES] = run;
}

// ---------------------------------------------------------------------------
// Stage B: per bucket — row_ptr, band-sort by src>>11, place into col_src
// ---------------------------------------------------------------------------
__global__ __launch_bounds__(256) void build_buckets(const uint32* __restrict__ packed,
                                                     const int* __restrict__ gcur,
                                                     const int* __restrict__ obase_arr,
                                                     int* __restrict__ row_ptr,
                                                     int* __restrict__ col_src) {
    __shared__ uint32 ed[BUCKET_CAP];
    __shared__ uint32 ed2[BUCKET_CAP];
    __shared__ int bandcur[N_BANDS];
    __shared__ int ncnt[BUCKET_NODES];
    __shared__ int ncur[BUCKET_NODES];
    int b = blockIdx.x, t = threadIdx.x;
    int cnt = gcur[b];
    if (cnt > BUCKET_CAP) cnt = BUCKET_CAP;
    int obase = obase_arr[b];
    int n0 = b * BUCKET_NODES;

    if (t < N_BANDS) bandcur[t] = 0;
    if (t < BUCKET_NODES) ncnt[t] = 0;
    __syncthreads();

    const uint32* reg = packed + (size_t)b * BUCKET_CAP;
    for (int i = t; i < cnt; i += 256) {
        uint32 v = reg[i];
        ed[i] = v;
        atomicAdd(&bandcur[(v & 0x1FFFFu) >> 11], 1);
        atomicAdd(&ncnt[v >> 17], 1);
    }
    __syncthreads();

    if (t == 0) {
        int run = 0;
        for (int w = 0; w < N_BANDS; ++w) {
            int c = bandcur[w];
            bandcur[w] = run;
            run += c;
        }
    }
    int myc = (t < BUCKET_NODES) ? ncnt[t] : 0;
    if (t < BUCKET_NODES) ncur[t] = myc;
    __syncthreads();
    for (int off = 1; off < BUCKET_NODES; off <<= 1) {
        int v = 0;
        if (t < BUCKET_NODES && t >= off) v = ncur[t - off];
        __syncthreads();
        if (t < BUCKET_NODES) ncur[t] += v;
        __syncthreads();
    }
    if (t < BUCKET_NODES) {
        int excl = ncur[t] - myc;
        ncur[t] = excl;
        int gn = n0 + t;
        if (gn < N_NODES) row_ptr[gn] = obase + excl;
    }
    __syncthreads();

    // counting sort by src band
    for (int i = t; i < cnt; i += 256) {
        uint32 v = ed[i];
        int p = atomicAdd(&bandcur[(v & 0x1FFFFu) >> 11], 1);
        ed2[p] = v;
    }
    __syncthreads();

    for (int i = t; i < cnt; i += 256) {
        uint32 v = ed2[i];
        int slot = atomicAdd(&ncur[v >> 17], 1);
        col_src[obase + slot] = (int)(v & 0x1FFFFu);
    }
}

// ---------------------------------------------------------------------------
// All 7 weight matrices -> WT bf16, transposed (n-major) AND pre-swizzled:
// element (n,k) at byte (n*256 + k*2) ^ ((n&7)<<4) within its matrix.
// ---------------------------------------------------------------------------
__global__ void cvt_wt_all(const float* __restrict__ Wn, const float* __restrict__ W1,
                           const float* __restrict__ W2, u16* __restrict__ WT) {
    int m = blockIdx.x >> 7, n = blockIdx.x & 127, k = threadIdx.x;
    const float* src = (m == 0) ? Wn
                     : (m <= 3) ? W1 + (size_t)(m - 1) * DIM * DIM
                                : W2 + (size_t)(m - 4) * DIM * DIM;
    int L = n * 256 + k * 2;
    int Ls = L ^ ((n & 7) << 4);
    *(u16*)((char*)WT + (size_t)m * 32768 + Ls) = f2bf(src[(size_t)k * DIM + n]);
}

// ---------------------------------------------------------------------------
// Aggregation (row-major, quad-per-edge): one wave per node; quad q loads one
// full 256 B row per edge via dwordx4 (16 B/lane), 4 edges in flight; f32
// accum; cross-quad shfl reduce. Structural at ~103 us / 357 MB fetch
// (falsified levers: fusion r4, pairing r7, col-slice r9, XCD-chunk r10).
// ---------------------------------------------------------------------------
__global__ __launch_bounds__(256) void aggregate_bf(const u16* __restrict__ h,
                                                    const int* __restrict__ row_ptr,
                                                    const int* __restrict__ col_src,
                                                    u16* __restrict__ agg) {
    int wg = (blockIdx.x & 7) * AGG_CHUNK + (blockIdx.x >> 3);  // bijective
    int wv = wg * 4 + (threadIdx.x >> 6);
    int lane = threadIdx.x & 63;
    int q = lane >> 4, c = lane & 15;
    if (wv >= N_NODES) return;
    int beg = row_ptr[wv], end = row_ptr[wv + 1];
    const uint4* h4 = (const uint4*)h;   // one row = 16 uint4

    float acc[8];
#pragma unroll
    for (int j = 0; j < 8; ++j) acc[j] = 0.f;

    if (q == 0) {  // self contribution (1+eps)*h, eps=0
        uint4 v = h4[(size_t)wv * 16 + c];
        unpack_add8(acc, v);
    }
    int e = beg + q;
    for (; e + 12 < end; e += 16) {
        int i0 = col_src[e];
        int i1 = col_src[e + 4];
        int i2 = col_src[e + 8];
        int i3 = col_src[e + 12];
        uint4 v0 = h4[(size_t)i0 * 16 + c];
        uint4 v1 = h4[(size_t)i1 * 16 + c];
        uint4 v2 = h4[(size_t)i2 * 16 + c];
        uint4 v3 = h4[(size_t)i3 * 16 + c];
        unpack_add8(acc, v0);
        unpack_add8(acc, v1);
        unpack_add8(acc, v2);
        unpack_add8(acc, v3);
    }
    for (; e < end; e += 4) {
        uint4 v0 = h4[(size_t)col_src[e] * 16 + c];
        unpack_add8(acc, v0);
    }
#pragma unroll
    for (int j = 0; j < 8; ++j) {
        acc[j] += __shfl_xor(acc[j], 16);
        acc[j] += __shfl_xor(acc[j], 32);
    }
    if (q == 0) {
        uint4 o;
        o.x = pack_bf2(acc[0], acc[1]);
        o.y = pack_bf2(acc[2], acc[3]);
        o.z = pack_bf2(acc[4], acc[5]);
        o.w = pack_bf2(acc[6], acc[7]);
        *(uint4*)&agg[(size_t)wv * DIM + c * 8] = o;
    }
}

// ---------------------------------------------------------------------------
// GEMM: 128 rows x 128 cols per block (256 thr = 4 waves).
// B (32 KB, pre-swizzled) in LDS; A loads hoisted before the stage barrier.
// MODE 0: A = f32 x (fused cvt)              -> h = A@W + b
// MODE 1: A = bf16 agg, BN stats epilogue    -> y = A@W1 + b1
// MODE 2: A = bf16 y, BN+ReLU pre, ReLU post -> h = relu(relu(BN(y))@W2+b2)
// (MODE-3 pool fusion REMOVED: r11 showed LDS-atomic epilogue cost +53 us.)
// ---------------------------------------------------------------------------
template <int MODE>
__global__ __launch_bounds__(256) void gemm_v2(const void* __restrict__ Av,
                                               const u16* __restrict__ WTs,
                                               const float* __restrict__ bias,
                                               u16* __restrict__ outp,
                                               float* __restrict__ bn_sum,
                                               float* __restrict__ bn_sumsq,
                                               const float* __restrict__ gamma,
                                               const float* __restrict__ beta) {
    __shared__ u16 sB[DIM * DIM];     // 32 KB swizzled
    __shared__ float sc_[DIM];
    __shared__ float sh_[DIM];
    __shared__ float ls[4][DIM];
    __shared__ float lq[4][DIM];

    int t = threadIdx.x;
    int wid = t >> 6, lane = t & 63;
    int hw = lane >> 4, c = lane & 15;
    int row0 = blockIdx.x * 128 + wid * 32;

    // ---- issue A loads FIRST ----
    bf16x8 a[2][4];
    float4 af[2][4][2];
#pragma unroll
    for (int rf = 0; rf < 2; ++rf) {
        int row = row0 + rf * 16 + c;
#pragma unroll
        for (int ks = 0; ks < 4; ++ks) {
            int k0 = ks * 32 + hw * 8;
            if (MODE == 0) {
                const float* xf = (const float*)Av;
                af[rf][ks][0] = make_float4(0.f, 0.f, 0.f, 0.f);
                af[rf][ks][1] = af[rf][ks][0];
                if (row < N_NODES) {
                    af[rf][ks][0] = *(const float4*)&xf[(size_t)row * DIM + k0];
                    af[rf][ks][1] = *(const float4*)&xf[(size_t)row * DIM + k0 + 4];
                }
            } else {
                const u16* Ab = (const u16*)Av;
                a[rf][ks] = *(const bf16x8*)&Ab[(size_t)row * DIM + k0];
            }
        }
    }

    // ---- stage B (linear copy; swizzle baked into global layout) ----
    {
        const uint4* Wg = (const uint4*)WTs;
        uint4* sB4 = (uint4*)sB;
#pragma unroll
        for (int i = 0; i < 8; ++i) sB4[i * 256 + t] = Wg[i * 256 + t];
    }
    if (MODE == 2 && t < DIM) {
        const float invN = 1.0f / (float)N_NODES;
        float mean = bn_sum[t] * invN;
        float var = fmaxf(bn_sumsq[t] * invN - mean * mean, 0.f);
        float rs = rsqrtf(var + BN_EPS);
        float sc = gamma[t] * rs;
        sc_[t] = sc;
        sh_[t] = beta[t] - mean * sc;
    }
    __syncthreads();

    // ---- finish A fragments in registers ----
#pragma unroll
    for (int rf = 0; rf < 2; ++rf) {
#pragma unroll
        for (int ks = 0; ks < 4; ++ks) {
            int k0 = ks * 32 + hw * 8;
            if (MODE == 0) {
                union { bf16x8 v; u16 u[8]; } ua;
                float4 v0 = af[rf][ks][0], v1 = af[rf][ks][1];
                ua.u[0] = f2bf(v0.x); ua.u[1] = f2bf(v0.y);
                ua.u[2] = f2bf(v0.z); ua.u[3] = f2bf(v0.w);
                ua.u[4] = f2bf(v1.x); ua.u[5] = f2bf(v1.y);
                ua.u[6] = f2bf(v1.z); ua.u[7] = f2bf(v1.w);
                a[rf][ks] = ua.v;
            } else if (MODE == 2) {
                union { bf16x8 v; u16 u[8]; } ua;
                ua.v = a[rf][ks];
#pragma unroll
                for (int j = 0; j < 8; ++j) {
                    float f = bf2f(ua.u[j]);
                    f = fmaxf(fmaf(f, sc_[k0 + j], sh_[k0 + j]), 0.f);
                    ua.u[j] = f2bf(f);
                }
                a[rf][ks] = ua.v;
            }
        }
    }

    // ---- MFMA from LDS B ----
    f32x4 acc[2][8];
#pragma unroll
    for (int rf = 0; rf < 2; ++rf)
#pragma unroll
        for (int nf = 0; nf < 8; ++nf) acc[rf][nf] = (f32x4){0.f, 0.f, 0.f, 0.f};

    int swz = (c & 7) << 4;
#pragma unroll
    for (int ks = 0; ks < 4; ++ks) {
#pragma unroll
        for (int nf = 0; nf < 8; ++nf) {
            int L = (nf * 4096 + c * 256 + ks * 64 + hw * 16) ^ swz;
            bf16x8 b = *(const bf16x8*)((const char*)sB + L);
            acc[0][nf] = __builtin_amdgcn_mfma_f32_16x16x32_bf16(a[0][ks], b, acc[0][nf], 0, 0, 0);
            acc[1][nf] = __builtin_amdgcn_mfma_f32_16x16x32_bf16(a[1][ks], b, acc[1][nf], 0, 0, 0);
        }
    }

    // ---- epilogue ----
    float s_[8], q_[8];
#pragma unroll
    for (int nf = 0; nf < 8; ++nf) { s_[nf] = 0.f; q_[nf] = 0.f; }

#pragma unroll
    for (int rf = 0; rf < 2; ++rf) {
        int rbase = row0 + rf * 16 + hw * 4;
#pragma unroll
        for (int nf = 0; nf < 8; ++nf) {
            float bv = bias[nf * 16 + c];
#pragma unroll
            for (int r = 0; r < 4; ++r) {
                float v = acc[rf][nf][r] + bv;
                if (MODE == 2) v = fmaxf(v, 0.f);
                outp[(size_t)(rbase + r) * DIM + nf * 16 + c] = f2bf(v);
                if (MODE == 1) {
                    float m = (rbase + r < N_NODES) ? v : 0.f;
                    s_[nf] += m;
                    q_[nf] += m * m;
                }
            }
        }
    }

    if (MODE == 1) {
#pragma unroll
        for (int nf = 0; nf < 8; ++nf) {
            s_[nf] += __shfl_xor(s_[nf], 16);
            s_[nf] += __shfl_xor(s_[nf], 32);
            q_[nf] += __shfl_xor(q_[nf], 16);
            q_[nf] += __shfl_xor(q_[nf], 32);
        }
        if (lane < 16) {
#pragma unroll
            for (int nf = 0; nf < 8; ++nf) {
                ls[wid][nf * 16 + c] = s_[nf];
                lq[wid][nf * 16 + c] = q_[nf];
            }
        }
        __syncthreads();
        if (t < DIM) {
            atomicAdd(&bn_sum[t], ls[0][t] + ls[1][t] + ls[2][t] + ls[3][t]);
            atomicAdd(&bn_sumsq[t], lq[0][t] + lq[1][t] + lq[2][t] + lq[3][t]);
        }
    }
}

// ---------------------------------------------------------------------------
// Global add pool (row-major bf16 h, f32 out); batch sorted
// ---------------------------------------------------------------------------
__global__ __launch_bounds__(256) void pool_bf(const u16* __restrict__ h,
                                               const int* __restrict__ batch,
                                               float* __restrict__ out) {
    int wv = (blockIdx.x * 256 + threadIdx.x) >> 6;
    int lane = threadIdx.x & 63;
    int base = wv * 32;
    if (base >= N_NODES) return;
    int end = base + 32;
    if (end > N_NODES) end = N_NODES;
    const uint32* h32 = (const uint32*)h;
    float ax = 0.f, ay = 0.f;
    int curg = batch[base];
    for (int n = base; n < end; ++n) {
        int g = batch[n];
        if (g != curg) {
            atomicAdd(&out[curg * DIM + lane * 2], ax);
            atomicAdd(&out[curg * DIM + lane * 2 + 1], ay);
            ax = 0.f;
            ay = 0.f;
            curg = g;
        }
        uint32 v = h32[(size_t)n * 64 + lane];
        ax += lo_bf(v);
        ay += hi_bf(v);
    }
    atomicAdd(&out[curg * DIM + lane * 2], ax);
    atomicAdd(&out[curg * DIM + lane * 2 + 1], ay);
}

// ---------------------------------------------------------------------------
extern "C" void kernel_launch(void* const* d_in, const int* in_sizes, int n_in,
                              void* d_out, int out_size, void* d_ws, size_t ws_size,
                              hipStream_t stream) {
    const float* x     = (const float*)d_in[0];
    const int*   ei    = (const int*)d_in[1];
    const int*   batch = (const int*)d_in[2];
    const float* Wn    = (const float*)d_in[3];
    const float* bnode = (const float*)d_in[4];
    const float* W1    = (const float*)d_in[5];
    const float* b1    = (const float*)d_in[6];
    const float* gamma = (const float*)d_in[7];
    const float* beta  = (const float*)d_in[8];
    const float* W2    = (const float*)d_in[9];
    const float* b2    = (const float*)d_in[10];
    float* out = (float*)d_out;

    const int* e_src = ei;
    const int* e_dst = ei + N_EDGES;

    // workspace layout
    const size_t MD = (size_t)M_PAD * DIM;
    u16* h   = (u16*)d_ws;                  // row-major
    u16* agg = h + MD;                      // row-major
    u16* y   = agg + MD;                    // row-major
    u16* WT  = y + MD;                      // 7 * 128 * 128 bf16, pre-swizzled
    int* row_ptr = (int*)(WT + 7 * DIM * DIM);
    int* col_src = row_ptr + N_NODES + 1;
    int* gcur    = col_src + N_EDGES;
    int* obase   = gcur + N_BUCKETS;
    float* bn_stats = (float*)(obase + N_BUCKETS);   // 3 layers * 2 * DIM
    // packed aliases y: used only during CSR build, before any GEMM writes y
    uint32* packed = (uint32*)y;            // 782*4864*4 B = 15.2 MB <= 25.6 MB

    const int GEMM_BLOCKS = M_PAD / 128;    // 782
    const int POOL_BLOCKS = (((N_NODES + 31) / 32) * 64 + 255) / 256;

    // ---- init + CSR build ----
    zero_misc<<<64, 256, 0, stream>>>(gcur, bn_stats, out,
                                      (uint32*)(agg + (size_t)N_NODES * DIM));
    bin_by_dst<<<BIN_BLOCKS, 256, 0, stream>>>(e_src, e_dst, gcur, packed);
    scan_buckets<<<1, 256, 0, stream>>>(gcur, obase, row_ptr);
    build_buckets<<<N_BUCKETS, 256, 0, stream>>>(packed, gcur, obase, row_ptr, col_src);

    // ---- weights (transposed + swizzled bf16) ----
    cvt_wt_all<<<7 * DIM, DIM, 0, stream>>>(Wn, W1, W2, WT);

    // ---- node encoder (fused f32->bf16) ----
    gemm_v2<0><<<GEMM_BLOCKS, 256, 0, stream>>>(x, WT, bnode, h, nullptr,
                                                nullptr, nullptr, nullptr);

    // ---- GIN layers ----
    for (int i = 0; i < N_LAYERS; ++i) {
        float* bn_sum = bn_stats + (size_t)i * 2 * DIM;
        float* bn_sumsq = bn_sum + DIM;
        aggregate_bf<<<AGG_BLOCKS, 256, 0, stream>>>(h, row_ptr, col_src, agg);
        gemm_v2<1><<<GEMM_BLOCKS, 256, 0, stream>>>(
            agg, WT + (size_t)(1 + i) * DIM * DIM, b1 + i * DIM, y, bn_sum,
            bn_sumsq, nullptr, nullptr);
        gemm_v2<2><<<GEMM_BLOCKS, 256, 0, stream>>>(
            y, WT + (size_t)(4 + i) * DIM * DIM, b2 + i * DIM, h, bn_sum,
            bn_sumsq, gamma + i * DIM, beta + i * DIM);
    }

    // ---- global add pool ----
    pool_bf<<<POOL_BLOCKS, 256, 0, stream>>>(h, batch, out);
}